// Round 1
// baseline (379.215 us; speedup 1.0000x reference)
//
#include <hip/hip_runtime.h>
#include <hip/hip_bf16.h>

// Pipeline: pack(x,wT) -> gemm_qkv(bf16 MFMA, scatter to q/k/vT) ->
//           flash attention (MFMA + online softmax) -> gemm_proj -> fp32 out.
// B=8 N=1024 C=768 H=12 D=64. All MFMA: v_mfma_f32_16x16x32_bf16.
// Verified layouts (guide §3): A: m=lane&15, k=quad*8+j ; B: n=lane&15, k=quad*8+j ;
// C/D: col=lane&15, row=quad*4+reg.

typedef __attribute__((ext_vector_type(8))) short bf16x8;
typedef __attribute__((ext_vector_type(4))) float f32x4;

__device__ __forceinline__ unsigned short f2bf(float f) {
    union { float f; unsigned u; } v; v.f = f;
    unsigned r = v.u + 0x7fff + ((v.u >> 16) & 1);   // RNE
    return (unsigned short)(r >> 16);
}

// ---------------- pack x: fp32 -> bf16 ----------------
__global__ void pack_x(const float* __restrict__ src, unsigned short* __restrict__ dst, int n4) {
    int i = blockIdx.x * blockDim.x + threadIdx.x;
    if (i < n4) {
        float4 v = ((const float4*)src)[i];
        ushort4 o;
        o.x = f2bf(v.x); o.y = f2bf(v.y); o.z = f2bf(v.z); o.w = f2bf(v.w);
        ((ushort4*)dst)[i] = o;
    }
}

// ---------------- transpose+pack weights: src (R x C) fp32 -> dst (C x R) bf16 ----------------
__global__ void transpose_pack(const float* __restrict__ src, unsigned short* __restrict__ dst,
                               int R, int C) {
    __shared__ float tile[64][65];
    int t = threadIdx.x;
    int c0 = blockIdx.x * 64, r0 = blockIdx.y * 64;
    int tr = t >> 4, tc4 = (t & 15) * 4;
    #pragma unroll
    for (int p = 0; p < 4; p++) {
        int r = tr + p * 16;
        float4 v = *(const float4*)&src[(size_t)(r0 + r) * C + c0 + tc4];
        tile[r][tc4 + 0] = v.x; tile[r][tc4 + 1] = v.y;
        tile[r][tc4 + 2] = v.z; tile[r][tc4 + 3] = v.w;
    }
    __syncthreads();
    #pragma unroll
    for (int p = 0; p < 4; p++) {
        int rr = tr + p * 16;              // index along C (output row)
        ushort4 o;
        o.x = f2bf(tile[tc4 + 0][rr]);
        o.y = f2bf(tile[tc4 + 1][rr]);
        o.z = f2bf(tile[tc4 + 2][rr]);
        o.w = f2bf(tile[tc4 + 3][rr]);
        *(ushort4*)&dst[(size_t)(c0 + rr) * R + r0 + tc4] = o;
    }
}

// ---------------- QKV GEMM: (8192x768)@(768x2304) -> scatter q,k,vT bf16 ----------------
__global__ __launch_bounds__(256, 2)
void gemm_qkv(const unsigned short* __restrict__ xb, const unsigned short* __restrict__ wT,
              const float* __restrict__ bias,
              unsigned short* __restrict__ qb, unsigned short* __restrict__ kb,
              unsigned short* __restrict__ vb) {
    const int K = 768;
    __shared__ unsigned short As[128 * 72];
    __shared__ unsigned short Bs[128 * 72];
    int t = threadIdx.x;
    int m0 = blockIdx.x * 128;
    int n0 = blockIdx.y * 128;
    int w = t >> 6, lane = t & 63, l16 = lane & 15, quad = lane >> 4;
    int wm = w >> 1, wn = w & 1;
    const f32x4 zero4 = {0.f, 0.f, 0.f, 0.f};
    f32x4 acc[4][4];
    #pragma unroll
    for (int a = 0; a < 4; a++)
        #pragma unroll
        for (int b = 0; b < 4; b++) acc[a][b] = zero4;

    int ar = t >> 3;           // 0..31
    int ac = (t & 7) * 8;      // 0..56
    const unsigned short* gA = xb + (size_t)(m0 + ar) * K + ac;
    const unsigned short* gB = wT + (size_t)(n0 + ar) * K + ac;

    for (int k0 = 0; k0 < K; k0 += 64) {
        __syncthreads();
        #pragma unroll
        for (int p = 0; p < 4; p++) {
            *(uint4*)&As[(ar + 32 * p) * 72 + ac] = *(const uint4*)(gA + (size_t)(32 * p) * K + k0);
            *(uint4*)&Bs[(ar + 32 * p) * 72 + ac] = *(const uint4*)(gB + (size_t)(32 * p) * K + k0);
        }
        __syncthreads();
        #pragma unroll
        for (int ks = 0; ks < 2; ks++) {
            bf16x8 af[4], bf[4];
            #pragma unroll
            for (int mi = 0; mi < 4; mi++)
                af[mi] = *(const bf16x8*)&As[(wm * 64 + mi * 16 + l16) * 72 + ks * 32 + quad * 8];
            #pragma unroll
            for (int ni = 0; ni < 4; ni++)
                bf[ni] = *(const bf16x8*)&Bs[(wn * 64 + ni * 16 + l16) * 72 + ks * 32 + quad * 8];
            #pragma unroll
            for (int mi = 0; mi < 4; mi++)
                #pragma unroll
                for (int ni = 0; ni < 4; ni++)
                    acc[mi][ni] = __builtin_amdgcn_mfma_f32_16x16x32_bf16(af[mi], bf[ni], acc[mi][ni], 0, 0, 0);
        }
    }

    // epilogue: col n = seg*768 + h*64 + d
    int nb = n0 + wn * 64;          // wave's 64-col base (one head, one segment)
    int seg = nb / 768;
    int nc = nb % 768;
    int h = nc >> 6;
    int bb = m0 >> 10;              // batch (128 | 1024)
    int bh = bb * 12 + h;
    float bv[4];
    #pragma unroll
    for (int ni = 0; ni < 4; ni++) bv[ni] = bias[nb + ni * 16 + l16];

    if (seg < 2) {
        unsigned short* dst = (seg == 0) ? qb : kb;
        #pragma unroll
        for (int mi = 0; mi < 4; mi++) {
            int nrow_base = (m0 & 1023) + wm * 64 + mi * 16 + quad * 4;
            #pragma unroll
            for (int i = 0; i < 4; i++) {
                unsigned short* drow = dst + ((size_t)bh * 1024 + nrow_base + i) * 64;
                #pragma unroll
                for (int ni = 0; ni < 4; ni++)
                    drow[ni * 16 + l16] = f2bf(acc[mi][ni][i] + bv[ni]);
            }
        }
    } else {
        #pragma unroll
        for (int mi = 0; mi < 4; mi++) {
            int nrow0 = (m0 & 1023) + wm * 64 + mi * 16 + quad * 4;
            #pragma unroll
            for (int ni = 0; ni < 4; ni++) {
                int d = ni * 16 + l16;
                ushort4 pk;
                pk.x = f2bf(acc[mi][ni][0] + bv[ni]);
                pk.y = f2bf(acc[mi][ni][1] + bv[ni]);
                pk.z = f2bf(acc[mi][ni][2] + bv[ni]);
                pk.w = f2bf(acc[mi][ni][3] + bv[ni]);
                *(ushort4*)&vb[((size_t)bh * 64 + d) * 1024 + nrow0] = pk;
            }
        }
    }
}

// ---------------- flash attention: block=(qblk,h,b), wave=16 queries ----------------
__global__ __launch_bounds__(256, 2)
void attn_kernel(const unsigned short* __restrict__ qb, const unsigned short* __restrict__ kb,
                 const unsigned short* __restrict__ vb, const float* __restrict__ temp,
                 unsigned short* __restrict__ attn) {
    __shared__ unsigned short Ps[64 * 72];
    int t = threadIdx.x, w = t >> 6, lane = t & 63, l16 = lane & 15, quad = lane >> 4;
    int qblk = blockIdx.x, h = blockIdx.y, bb = blockIdx.z;
    int bh = bb * 12 + h;
    float tmp = temp[h];
    int qbase = qblk * 64 + w * 16;

    const unsigned short* qrow = qb + ((size_t)bh * 1024 + qbase + l16) * 64;
    bf16x8 aq0 = *(const bf16x8*)&qrow[quad * 8];
    bf16x8 aq1 = *(const bf16x8*)&qrow[32 + quad * 8];

    const f32x4 zero4 = {0.f, 0.f, 0.f, 0.f};
    float m_i[4], l_i[4];
    f32x4 Oacc[4];
    #pragma unroll
    for (int i = 0; i < 4; i++) { m_i[i] = -1e30f; l_i[i] = 0.f; }
    #pragma unroll
    for (int ti = 0; ti < 4; ti++) Oacc[ti] = zero4;

    unsigned short* pw = &Ps[w * 16 * 72];
    const unsigned short* kbase = kb + (size_t)bh * 1024 * 64;
    const unsigned short* vbase = vb + (size_t)bh * 64 * 1024;

    for (int kt = 0; kt < 16; kt++) {
        // S = Q K^T  (16 q-rows x 64 keys per wave)
        f32x4 s[4];
        #pragma unroll
        for (int ni = 0; ni < 4; ni++) {
            const unsigned short* krow = kbase + (size_t)(kt * 64 + ni * 16 + l16) * 64;
            bf16x8 bk0 = *(const bf16x8*)&krow[quad * 8];
            bf16x8 bk1 = *(const bf16x8*)&krow[32 + quad * 8];
            f32x4 z = zero4;
            z = __builtin_amdgcn_mfma_f32_16x16x32_bf16(aq0, bk0, z, 0, 0, 0);
            z = __builtin_amdgcn_mfma_f32_16x16x32_bf16(aq1, bk1, z, 0, 0, 0);
            s[ni] = z;
        }
        // temperature scale + diagonal mask + row max
        float rm[4];
        #pragma unroll
        for (int i = 0; i < 4; i++) rm[i] = -1e30f;
        #pragma unroll
        for (int ni = 0; ni < 4; ni++)
            #pragma unroll
            for (int i = 0; i < 4; i++) {
                float v = s[ni][i] * tmp;
                int keyg = kt * 64 + ni * 16 + l16;
                int qg = qbase + quad * 4 + i;
                if (keyg == qg) v = -1e30f;
                s[ni][i] = v;
                rm[i] = fmaxf(rm[i], v);
            }
        #pragma unroll
        for (int off = 1; off < 16; off <<= 1)
            #pragma unroll
            for (int i = 0; i < 4; i++) rm[i] = fmaxf(rm[i], __shfl_xor(rm[i], off));

        float alpha[4], rs[4];
        #pragma unroll
        for (int i = 0; i < 4; i++) {
            float mn = fmaxf(m_i[i], rm[i]);
            alpha[i] = __expf(m_i[i] - mn);
            m_i[i] = mn;
            rs[i] = 0.f;
        }
        // P = exp(S - m), write to LDS (row-major, stride 72)
        #pragma unroll
        for (int ni = 0; ni < 4; ni++)
            #pragma unroll
            for (int i = 0; i < 4; i++) {
                float p = __expf(s[ni][i] - m_i[i]);
                rs[i] += p;
                pw[(quad * 4 + i) * 72 + ni * 16 + l16] = f2bf(p);
            }
        #pragma unroll
        for (int off = 1; off < 16; off <<= 1)
            #pragma unroll
            for (int i = 0; i < 4; i++) rs[i] += __shfl_xor(rs[i], off);
        #pragma unroll
        for (int i = 0; i < 4; i++) l_i[i] = l_i[i] * alpha[i] + rs[i];
        #pragma unroll
        for (int ti = 0; ti < 4; ti++)
            #pragma unroll
            for (int i = 0; i < 4; i++) Oacc[ti][i] *= alpha[i];

        // O += P V   (A-frags of P from LDS; B-frags of V from global vT)
        bf16x8 ap0 = *(const bf16x8*)&pw[l16 * 72 + quad * 8];
        bf16x8 ap1 = *(const bf16x8*)&pw[l16 * 72 + 32 + quad * 8];
        #pragma unroll
        for (int ti = 0; ti < 4; ti++) {
            const unsigned short* vrow = vbase + (size_t)(ti * 16 + l16) * 1024 + kt * 64;
            bf16x8 bv0 = *(const bf16x8*)&vrow[quad * 8];
            bf16x8 bv1 = *(const bf16x8*)&vrow[32 + quad * 8];
            Oacc[ti] = __builtin_amdgcn_mfma_f32_16x16x32_bf16(ap0, bv0, Oacc[ti], 0, 0, 0);
            Oacc[ti] = __builtin_amdgcn_mfma_f32_16x16x32_bf16(ap1, bv1, Oacc[ti], 0, 0, 0);
        }
    }

    // epilogue: normalize, write bf16 attn_out (B*N x 768), col = h*64 + d
    float inv[4];
    #pragma unroll
    for (int i = 0; i < 4; i++) inv[i] = 1.0f / l_i[i];
    #pragma unroll
    for (int ti = 0; ti < 4; ti++)
        #pragma unroll
        for (int i = 0; i < 4; i++) {
            int nq = qbase + quad * 4 + i;
            int col = h * 64 + ti * 16 + l16;
            attn[((size_t)bb * 1024 + nq) * 768 + col] = f2bf(Oacc[ti][i] * inv[i]);
        }
}

// ---------------- proj GEMM: (8192x768)@(768x768) + bias -> fp32 out ----------------
__global__ __launch_bounds__(256, 2)
void gemm_proj(const unsigned short* __restrict__ ab, const unsigned short* __restrict__ wT,
               const float* __restrict__ bias, float* __restrict__ out) {
    const int K = 768;
    __shared__ unsigned short As[128 * 72];
    __shared__ unsigned short Bs[128 * 72];
    int t = threadIdx.x;
    int m0 = blockIdx.x * 128;
    int n0 = blockIdx.y * 128;
    int w = t >> 6, lane = t & 63, l16 = lane & 15, quad = lane >> 4;
    int wm = w >> 1, wn = w & 1;
    const f32x4 zero4 = {0.f, 0.f, 0.f, 0.f};
    f32x4 acc[4][4];
    #pragma unroll
    for (int a = 0; a < 4; a++)
        #pragma unroll
        for (int b = 0; b < 4; b++) acc[a][b] = zero4;

    int ar = t >> 3;
    int ac = (t & 7) * 8;
    const unsigned short* gA = ab + (size_t)(m0 + ar) * K + ac;
    const unsigned short* gB = wT + (size_t)(n0 + ar) * K + ac;

    for (int k0 = 0; k0 < K; k0 += 64) {
        __syncthreads();
        #pragma unroll
        for (int p = 0; p < 4; p++) {
            *(uint4*)&As[(ar + 32 * p) * 72 + ac] = *(const uint4*)(gA + (size_t)(32 * p) * K + k0);
            *(uint4*)&Bs[(ar + 32 * p) * 72 + ac] = *(const uint4*)(gB + (size_t)(32 * p) * K + k0);
        }
        __syncthreads();
        #pragma unroll
        for (int ks = 0; ks < 2; ks++) {
            bf16x8 af[4], bf[4];
            #pragma unroll
            for (int mi = 0; mi < 4; mi++)
                af[mi] = *(const bf16x8*)&As[(wm * 64 + mi * 16 + l16) * 72 + ks * 32 + quad * 8];
            #pragma unroll
            for (int ni = 0; ni < 4; ni++)
                bf[ni] = *(const bf16x8*)&Bs[(wn * 64 + ni * 16 + l16) * 72 + ks * 32 + quad * 8];
            #pragma unroll
            for (int mi = 0; mi < 4; mi++)
                #pragma unroll
                for (int ni = 0; ni < 4; ni++)
                    acc[mi][ni] = __builtin_amdgcn_mfma_f32_16x16x32_bf16(af[mi], bf[ni], acc[mi][ni], 0, 0, 0);
        }
    }

    #pragma unroll
    for (int mi = 0; mi < 4; mi++)
        #pragma unroll
        for (int i = 0; i < 4; i++) {
            int row = m0 + wm * 64 + mi * 16 + quad * 4 + i;
            float* orow = out + (size_t)row * 768;
            #pragma unroll
            for (int ni = 0; ni < 4; ni++) {
                int col = n0 + wn * 64 + ni * 16 + l16;
                orow[col] = acc[mi][ni][i] + bias[col];
            }
        }
}

extern "C" void kernel_launch(void* const* d_in, const int* in_sizes, int n_in,
                              void* d_out, int out_size, void* d_ws, size_t ws_size,
                              hipStream_t stream) {
    const float* x      = (const float*)d_in[0];
    const float* w_qkv  = (const float*)d_in[1];
    const float* b_qkv  = (const float*)d_in[2];
    const float* w_proj = (const float*)d_in[3];
    const float* b_proj = (const float*)d_in[4];
    const float* temp   = (const float*)d_in[5];
    float* out = (float*)d_out;

    char* ws = (char*)d_ws;
    unsigned short* xb     = (unsigned short*)(ws);                 // 8192x768 bf16
    unsigned short* wqkvT  = (unsigned short*)(ws + 12582912);      // 2304x768 bf16
    unsigned short* wprojT = (unsigned short*)(ws + 16121856);      // 768x768 bf16
    unsigned short* qb     = (unsigned short*)(ws + 17301504);      // (B H N D) bf16
    unsigned short* kb     = (unsigned short*)(ws + 29884416);      // (B H N D) bf16
    unsigned short* vb     = (unsigned short*)(ws + 42467328);      // (B H D N) bf16
    unsigned short* attn   = (unsigned short*)(ws + 55050240);      // 8192x768 bf16

    pack_x<<<6144, 256, 0, stream>>>(x, xb, 1572864);
    transpose_pack<<<dim3(36, 12), 256, 0, stream>>>(w_qkv, wqkvT, 768, 2304);
    transpose_pack<<<dim3(12, 12), 256, 0, stream>>>(w_proj, wprojT, 768, 768);
    gemm_qkv<<<dim3(64, 18), 256, 0, stream>>>(xb, wqkvT, b_qkv, qb, kb, vb);
    attn_kernel<<<dim3(16, 12, 8), 256, 0, stream>>>(qb, kb, vb, temp, attn);
    gemm_proj<<<dim3(64, 6), 256, 0, stream>>>(attn, wprojT, b_proj, out);
}

// Round 2
// 215.769 us; speedup vs baseline: 1.7575x; 1.7575x over previous
//
#include <hip/hip_runtime.h>
#include <hip/hip_bf16.h>

// B=8 N=1024 C=768 H=12 D=64.  All MFMA: v_mfma_f32_16x16x32_bf16.
// Layouts (verified): A: m=lane&15, k=quad*8+j ; B: n=lane&15, k=quad*8+j ;
// C/D: col=lane&15, row=quad*4+reg.
//
// LDS tiles are stride-64-shorts with XOR swizzle: element (row, chunk) lives at
// row*64 + ((chunk ^ (row&7))<<3) shorts (chunk = 8-short group). This keeps
// global_load_lds legal (no padding) and caps ds_read_b128 conflicts at 2-way (free).

typedef __attribute__((ext_vector_type(8))) short bf16x8;
typedef __attribute__((ext_vector_type(4))) float f32x4;

__device__ __forceinline__ unsigned short f2bf(float f) {
    union { float f; unsigned u; } v; v.f = f;
    unsigned r = v.u + 0x7fff + ((v.u >> 16) & 1);   // RNE
    return (unsigned short)(r >> 16);
}

__device__ __forceinline__ void gl_lds16(const unsigned short* g, unsigned short* l) {
    __builtin_amdgcn_global_load_lds(
        (const __attribute__((address_space(1))) void*)g,
        (__attribute__((address_space(3))) void*)l, 16, 0, 0);
}

// read a bf16x8 fragment chunk from a swizzled stride-64 LDS tile
__device__ __forceinline__ bf16x8 rd_sw(const unsigned short* lds, int row, int chunk) {
    return *(const bf16x8*)&lds[row * 64 + (((chunk ^ (row & 7))) << 3)];
}

// stage a 64-row x 64-short tile (row stride gstride shorts) into swizzled LDS (8KB)
__device__ __forceinline__ void stage64(const unsigned short* g, int gstride,
                                        unsigned short* lds, int t) {
    int row0 = t >> 3, c = t & 7;
    #pragma unroll
    for (int r = 0; r < 2; r++) {
        int row = r * 32 + row0;
        gl_lds16(g + (size_t)row * gstride + ((c ^ (row & 7)) << 3),
                 lds + r * 2048 + ((t >> 6) << 9));   // wave-uniform base; HW adds lane*16B
    }
}

// ---------------- pack x: fp32 -> bf16 ----------------
__global__ void pack_x(const float* __restrict__ src, unsigned short* __restrict__ dst, int n4) {
    int i = blockIdx.x * blockDim.x + threadIdx.x;
    if (i < n4) {
        float4 v = ((const float4*)src)[i];
        ushort4 o;
        o.x = f2bf(v.x); o.y = f2bf(v.y); o.z = f2bf(v.z); o.w = f2bf(v.w);
        ((ushort4*)dst)[i] = o;
    }
}

// ---------------- transpose+pack weights: src (R x C) fp32 -> dst (C x R) bf16 ----------------
__global__ void transpose_pack(const float* __restrict__ src, unsigned short* __restrict__ dst,
                               int R, int C) {
    __shared__ float tile[64][65];
    int t = threadIdx.x;
    int c0 = blockIdx.x * 64, r0 = blockIdx.y * 64;
    int tr = t >> 4, tc4 = (t & 15) * 4;
    #pragma unroll
    for (int p = 0; p < 4; p++) {
        int r = tr + p * 16;
        float4 v = *(const float4*)&src[(size_t)(r0 + r) * C + c0 + tc4];
        tile[r][tc4 + 0] = v.x; tile[r][tc4 + 1] = v.y;
        tile[r][tc4 + 2] = v.z; tile[r][tc4 + 3] = v.w;
    }
    __syncthreads();
    #pragma unroll
    for (int p = 0; p < 4; p++) {
        int rr = tr + p * 16;
        ushort4 o;
        o.x = f2bf(tile[tc4 + 0][rr]);
        o.y = f2bf(tile[tc4 + 1][rr]);
        o.z = f2bf(tile[tc4 + 2][rr]);
        o.w = f2bf(tile[tc4 + 3][rr]);
        *(ushort4*)&dst[(size_t)(c0 + rr) * R + r0 + tc4] = o;
    }
}

// ---------------- QKV GEMM: (8192x768)@(768x2304) -> scatter q,k,vT bf16 ----------------
__global__ __launch_bounds__(256, 2)
void gemm_qkv(const unsigned short* __restrict__ xb, const unsigned short* __restrict__ wT,
              const float* __restrict__ bias,
              unsigned short* __restrict__ qb, unsigned short* __restrict__ kb,
              unsigned short* __restrict__ vb) {
    const int K = 768;
    __shared__ unsigned short As[8192];   // 128 x 64 swizzled
    __shared__ unsigned short Bs[8192];
    int t = threadIdx.x;
    int m0 = blockIdx.x * 128;
    int n0 = blockIdx.y * 128;
    int w = t >> 6, lane = t & 63, l16 = lane & 15, quad = lane >> 4;
    int wm = w >> 1, wn = w & 1;
    const f32x4 zero4 = {0.f, 0.f, 0.f, 0.f};
    f32x4 acc[4][4];
    #pragma unroll
    for (int a = 0; a < 4; a++)
        #pragma unroll
        for (int b = 0; b < 4; b++) acc[a][b] = zero4;

    int row0 = t >> 3, ch = t & 7;
    const unsigned short* gA = xb + (size_t)m0 * K;
    const unsigned short* gB = wT + (size_t)n0 * K;

    for (int k0 = 0; k0 < K; k0 += 64) {
        __syncthreads();
        #pragma unroll
        for (int r = 0; r < 4; r++) {
            int row = r * 32 + row0;
            int gc = k0 + ((ch ^ (row & 7)) << 3);
            unsigned short* lp = (unsigned short*)((char*)0 + 0); (void)lp;
            gl_lds16(gA + (size_t)row * K + gc, As + r * 2048 + ((t >> 6) << 9));
            gl_lds16(gB + (size_t)row * K + gc, Bs + r * 2048 + ((t >> 6) << 9));
        }
        __syncthreads();
        #pragma unroll
        for (int ks = 0; ks < 2; ks++) {
            bf16x8 af[4], bf[4];
            #pragma unroll
            for (int mi = 0; mi < 4; mi++)
                af[mi] = rd_sw(As, wm * 64 + mi * 16 + l16, ks * 4 + quad);
            #pragma unroll
            for (int ni = 0; ni < 4; ni++)
                bf[ni] = rd_sw(Bs, wn * 64 + ni * 16 + l16, ks * 4 + quad);
            #pragma unroll
            for (int mi = 0; mi < 4; mi++)
                #pragma unroll
                for (int ni = 0; ni < 4; ni++)
                    acc[mi][ni] = __builtin_amdgcn_mfma_f32_16x16x32_bf16(af[mi], bf[ni], acc[mi][ni], 0, 0, 0);
        }
    }

    // epilogue: col n = seg*768 + h*64 + d
    int nb = n0 + wn * 64;
    int seg = nb / 768;
    int nc = nb % 768;
    int h = nc >> 6;
    int bb = m0 >> 10;
    int bh = bb * 12 + h;
    float bv[4];
    #pragma unroll
    for (int ni = 0; ni < 4; ni++) bv[ni] = bias[nb + ni * 16 + l16];

    if (seg < 2) {
        unsigned short* dst = (seg == 0) ? qb : kb;
        #pragma unroll
        for (int mi = 0; mi < 4; mi++) {
            int nrow_base = (m0 & 1023) + wm * 64 + mi * 16 + quad * 4;
            #pragma unroll
            for (int i = 0; i < 4; i++) {
                unsigned short* drow = dst + ((size_t)bh * 1024 + nrow_base + i) * 64;
                #pragma unroll
                for (int ni = 0; ni < 4; ni++)
                    drow[ni * 16 + l16] = f2bf(acc[mi][ni][i] + bv[ni]);
            }
        }
    } else {
        #pragma unroll
        for (int mi = 0; mi < 4; mi++) {
            int nrow0 = (m0 & 1023) + wm * 64 + mi * 16 + quad * 4;
            #pragma unroll
            for (int ni = 0; ni < 4; ni++) {
                int d = ni * 16 + l16;
                ushort4 pk;
                pk.x = f2bf(acc[mi][ni][0] + bv[ni]);
                pk.y = f2bf(acc[mi][ni][1] + bv[ni]);
                pk.z = f2bf(acc[mi][ni][2] + bv[ni]);
                pk.w = f2bf(acc[mi][ni][3] + bv[ni]);
                *(ushort4*)&vb[((size_t)bh * 64 + d) * 1024 + nrow0] = pk;
            }
        }
    }
}

// ---------------- flash attention ----------------
// grid (96, 16): blockIdx.x = b*12+h (fast dim -> all 16 q-blocks of one (b,h)
// land on the same XCD under round-robin dispatch => K/V served from that XCD's L2).
__global__ __launch_bounds__(256, 4)
void attn_kernel(const unsigned short* __restrict__ qb, const unsigned short* __restrict__ kb,
                 const unsigned short* __restrict__ vb, const float* __restrict__ temp,
                 unsigned short* __restrict__ attn) {
    __shared__ unsigned short Kt[2][4096];   // 64 keys x 64 d, swizzled
    __shared__ unsigned short Vt[2][4096];   // 64 d x 64 keys, swizzled
    __shared__ unsigned short Ps[4][1024];   // per-wave 16 q x 64 keys, swizzled
    int t = threadIdx.x, w = t >> 6, lane = t & 63, l16 = lane & 15, quad = lane >> 4;
    int bh = blockIdx.x, qblk = blockIdx.y;
    int bb = bh / 12, h = bh % 12;
    float tscale = temp[h] * 1.44269504088896f;   // temp * log2(e); softmax in base-2
    int qbase = qblk * 64 + w * 16;

    const unsigned short* kbase = kb + (size_t)bh * 65536;
    const unsigned short* vbase = vb + (size_t)bh * 65536;

    // stage tile 0
    stage64(kbase, 64, Kt[0], t);
    stage64(vbase, 1024, Vt[0], t);

    const unsigned short* qrow = qb + ((size_t)bh * 1024 + qbase + l16) * 64;
    bf16x8 aq0 = *(const bf16x8*)&qrow[quad * 8];
    bf16x8 aq1 = *(const bf16x8*)&qrow[32 + quad * 8];

    bf16x8 vone;
    #pragma unroll
    for (int j = 0; j < 8; j++) vone[j] = (short)0x3F80;   // bf16 1.0

    const f32x4 zero4 = {0.f, 0.f, 0.f, 0.f};
    float m_i[4];
    f32x4 Oacc[4];
    f32x4 Osum = zero4;            // row sums via ones-MFMA (replaces shuffle reduction)
    #pragma unroll
    for (int i = 0; i < 4; i++) m_i[i] = -3e38f;
    #pragma unroll
    for (int ti = 0; ti < 4; ti++) Oacc[ti] = zero4;

    unsigned short* pw = Ps[w];

    for (int kt = 0; kt < 16; kt++) {
        int cur = kt & 1;
        __syncthreads();                       // prev prefetch visible; prev reads done
        if (kt < 15) {                         // distance-1 prefetch (drained at next barrier)
            stage64(kbase + (size_t)(kt + 1) * 4096, 64, Kt[cur ^ 1], t);
            stage64(vbase + (size_t)(kt + 1) * 64, 1024, Vt[cur ^ 1], t);
        }
        const unsigned short* Kc = Kt[cur];
        const unsigned short* Vc = Vt[cur];

        // S = Q K^T  (16 q x 64 keys per wave)
        f32x4 s[4];
        #pragma unroll
        for (int ni = 0; ni < 4; ni++) {
            bf16x8 bk0 = rd_sw(Kc, ni * 16 + l16, quad);
            bf16x8 bk1 = rd_sw(Kc, ni * 16 + l16, 4 + quad);
            f32x4 z = zero4;
            z = __builtin_amdgcn_mfma_f32_16x16x32_bf16(aq0, bk0, z, 0, 0, 0);
            z = __builtin_amdgcn_mfma_f32_16x16x32_bf16(aq1, bk1, z, 0, 0, 0);
            s[ni] = z;
        }

        // scale (+ diag mask only on the one intersecting tile) + row max
        bool diag = (kt == qblk);
        float rm[4];
        #pragma unroll
        for (int i = 0; i < 4; i++) rm[i] = -3e38f;
        #pragma unroll
        for (int ni = 0; ni < 4; ni++)
            #pragma unroll
            for (int i = 0; i < 4; i++) {
                float v = s[ni][i] * tscale;
                if (diag && ni == w && l16 == quad * 4 + i) v = -3e38f;
                s[ni][i] = v;
                rm[i] = fmaxf(rm[i], v);
            }
        #pragma unroll
        for (int off = 1; off < 16; off <<= 1)
            #pragma unroll
            for (int i = 0; i < 4; i++) rm[i] = fmaxf(rm[i], __shfl_xor(rm[i], off));

        float alpha[4];
        #pragma unroll
        for (int i = 0; i < 4; i++) {
            float mn = fmaxf(m_i[i], rm[i]);
            alpha[i] = exp2f(m_i[i] - mn);
            m_i[i] = mn;
        }
        #pragma unroll
        for (int i = 0; i < 4; i++) Osum[i] *= alpha[i];
        #pragma unroll
        for (int ti = 0; ti < 4; ti++)
            #pragma unroll
            for (int i = 0; i < 4; i++) Oacc[ti][i] *= alpha[i];

        // P = 2^(S-m) -> swizzled LDS (bf16)
        #pragma unroll
        for (int ni = 0; ni < 4; ni++)
            #pragma unroll
            for (int i = 0; i < 4; i++) {
                float p = exp2f(s[ni][i] - m_i[i]);
                int r = quad * 4 + i;
                pw[r * 64 + (((ni * 2 + (l16 >> 3)) ^ (r & 7)) << 3) + (l16 & 7)] = f2bf(p);
            }

        bf16x8 ap0 = rd_sw(pw, l16, quad);
        bf16x8 ap1 = rd_sw(pw, l16, 4 + quad);

        // row sums: P @ ones (C layout: every column holds the row sum)
        Osum = __builtin_amdgcn_mfma_f32_16x16x32_bf16(ap0, vone, Osum, 0, 0, 0);
        Osum = __builtin_amdgcn_mfma_f32_16x16x32_bf16(ap1, vone, Osum, 0, 0, 0);

        // O += P V
        #pragma unroll
        for (int ti = 0; ti < 4; ti++) {
            bf16x8 bv0 = rd_sw(Vc, ti * 16 + l16, quad);
            bf16x8 bv1 = rd_sw(Vc, ti * 16 + l16, 4 + quad);
            Oacc[ti] = __builtin_amdgcn_mfma_f32_16x16x32_bf16(ap0, bv0, Oacc[ti], 0, 0, 0);
            Oacc[ti] = __builtin_amdgcn_mfma_f32_16x16x32_bf16(ap1, bv1, Oacc[ti], 0, 0, 0);
        }
    }

    float inv[4];
    #pragma unroll
    for (int i = 0; i < 4; i++) inv[i] = 1.0f / Osum[i];
    #pragma unroll
    for (int ti = 0; ti < 4; ti++)
        #pragma unroll
        for (int i = 0; i < 4; i++) {
            int nq = qbase + quad * 4 + i;
            int col = h * 64 + ti * 16 + l16;
            attn[((size_t)bb * 1024 + nq) * 768 + col] = f2bf(Oacc[ti][i] * inv[i]);
        }
}

// ---------------- proj GEMM: (8192x768)@(768x768) + bias -> fp32 out ----------------
__global__ __launch_bounds__(256, 2)
void gemm_proj(const unsigned short* __restrict__ ab, const unsigned short* __restrict__ wT,
               const float* __restrict__ bias, float* __restrict__ out) {
    const int K = 768;
    __shared__ unsigned short As[8192];
    __shared__ unsigned short Bs[8192];
    int t = threadIdx.x;
    int m0 = blockIdx.x * 128;
    int n0 = blockIdx.y * 128;
    int w = t >> 6, lane = t & 63, l16 = lane & 15, quad = lane >> 4;
    int wm = w >> 1, wn = w & 1;
    const f32x4 zero4 = {0.f, 0.f, 0.f, 0.f};
    f32x4 acc[4][4];
    #pragma unroll
    for (int a = 0; a < 4; a++)
        #pragma unroll
        for (int b = 0; b < 4; b++) acc[a][b] = zero4;

    int row0 = t >> 3, ch = t & 7;
    const unsigned short* gA = ab + (size_t)m0 * K;
    const unsigned short* gB = wT + (size_t)n0 * K;

    for (int k0 = 0; k0 < K; k0 += 64) {
        __syncthreads();
        #pragma unroll
        for (int r = 0; r < 4; r++) {
            int row = r * 32 + row0;
            int gc = k0 + ((ch ^ (row & 7)) << 3);
            gl_lds16(gA + (size_t)row * K + gc, As + r * 2048 + ((t >> 6) << 9));
            gl_lds16(gB + (size_t)row * K + gc, Bs + r * 2048 + ((t >> 6) << 9));
        }
        __syncthreads();
        #pragma unroll
        for (int ks = 0; ks < 2; ks++) {
            bf16x8 af[4], bf[4];
            #pragma unroll
            for (int mi = 0; mi < 4; mi++)
                af[mi] = rd_sw(As, wm * 64 + mi * 16 + l16, ks * 4 + quad);
            #pragma unroll
            for (int ni = 0; ni < 4; ni++)
                bf[ni] = rd_sw(Bs, wn * 64 + ni * 16 + l16, ks * 4 + quad);
            #pragma unroll
            for (int mi = 0; mi < 4; mi++)
                #pragma unroll
                for (int ni = 0; ni < 4; ni++)
                    acc[mi][ni] = __builtin_amdgcn_mfma_f32_16x16x32_bf16(af[mi], bf[ni], acc[mi][ni], 0, 0, 0);
        }
    }

    #pragma unroll
    for (int mi = 0; mi < 4; mi++)
        #pragma unroll
        for (int i = 0; i < 4; i++) {
            int row = m0 + wm * 64 + mi * 16 + quad * 4 + i;
            float* orow = out + (size_t)row * 768;
            #pragma unroll
            for (int ni = 0; ni < 4; ni++) {
                int col = n0 + wn * 64 + ni * 16 + l16;
                orow[col] = acc[mi][ni][i] + bias[col];
            }
        }
}

extern "C" void kernel_launch(void* const* d_in, const int* in_sizes, int n_in,
                              void* d_out, int out_size, void* d_ws, size_t ws_size,
                              hipStream_t stream) {
    const float* x      = (const float*)d_in[0];
    const float* w_qkv  = (const float*)d_in[1];
    const float* b_qkv  = (const float*)d_in[2];
    const float* w_proj = (const float*)d_in[3];
    const float* b_proj = (const float*)d_in[4];
    const float* temp   = (const float*)d_in[5];
    float* out = (float*)d_out;

    char* ws = (char*)d_ws;
    unsigned short* xb     = (unsigned short*)(ws);                 // 8192x768 bf16
    unsigned short* wqkvT  = (unsigned short*)(ws + 12582912);      // 2304x768 bf16
    unsigned short* wprojT = (unsigned short*)(ws + 16121856);      // 768x768 bf16
    unsigned short* qb     = (unsigned short*)(ws + 17301504);      // (B H N D) bf16
    unsigned short* kb     = (unsigned short*)(ws + 29884416);      // (B H N D) bf16
    unsigned short* vb     = (unsigned short*)(ws + 42467328);      // (B H D N) bf16
    unsigned short* attn   = (unsigned short*)(ws + 55050240);      // 8192x768 bf16

    pack_x<<<6144, 256, 0, stream>>>(x, xb, 1572864);
    transpose_pack<<<dim3(36, 12), 256, 0, stream>>>(w_qkv, wqkvT, 768, 2304);
    transpose_pack<<<dim3(12, 12), 256, 0, stream>>>(w_proj, wprojT, 768, 768);
    gemm_qkv<<<dim3(64, 18), 256, 0, stream>>>(xb, wqkvT, b_qkv, qb, kb, vb);
    attn_kernel<<<dim3(96, 16), 256, 0, stream>>>(qb, kb, vb, temp, attn);
    gemm_proj<<<dim3(64, 6), 256, 0, stream>>>(attn, wprojT, b_proj, out);
}

// Round 3
// 208.177 us; speedup vs baseline: 1.8216x; 1.0365x over previous
//
#include <hip/hip_runtime.h>
#include <hip/hip_bf16.h>

// B=8 N=1024 C=768 H=12 D=64.  All MFMA: v_mfma_f32_16x16x32_bf16.
// Frag layouts (verified): A: m=lane&15, k=quad*8+j ; B: n=lane&15, k=quad*8+j ;
// C/D: col=lane&15, row=quad*4+reg.
//
// Attention computes S^T = K·Q^T (A=K, B=Q) so the C-layout puts q on lanes and
// keys on regs: P^T rows (4 consecutive keys) pack into one ds_write_b64, and
// PV runs as O^T = V^T·P^T with the P^T B-frags read as 2 ds_read_b128 shared
// across all d-tiles. Softmax uses a fixed max (0): scores bounded (~2^36 max in
// exp2 domain, fp32-safe), numerator/denominator share bf16 P so scaling cancels.
//
// K/V LDS tiles are stride-64 shorts with XOR swizzle: (row, chunk) at
// row*64 + ((chunk ^ (row&7))<<3) — keeps global_load_lds legal (no padding),
// caps ds conflicts at 2-way (free). P^T uses its own swizzle (see below).

typedef __attribute__((ext_vector_type(8))) short bf16x8;
typedef __attribute__((ext_vector_type(4))) float f32x4;

__device__ __forceinline__ unsigned short f2bf(float f) {
    union { float f; unsigned u; } v; v.f = f;
    unsigned r = v.u + 0x7fff + ((v.u >> 16) & 1);   // RNE
    return (unsigned short)(r >> 16);
}

__device__ __forceinline__ void gl_lds16(const unsigned short* g, unsigned short* l) {
    __builtin_amdgcn_global_load_lds(
        (const __attribute__((address_space(1))) void*)g,
        (__attribute__((address_space(3))) void*)l, 16, 0, 0);
}

// read a bf16x8 fragment chunk from a swizzled stride-64 LDS tile
__device__ __forceinline__ bf16x8 rd_sw(const unsigned short* lds, int row, int chunk) {
    return *(const bf16x8*)&lds[row * 64 + (((chunk ^ (row & 7))) << 3)];
}

// stage a 64-row x 64-short tile (row stride gstride shorts) into swizzled LDS (8KB)
__device__ __forceinline__ void stage64(const unsigned short* g, int gstride,
                                        unsigned short* lds, int t) {
    int row0 = t >> 3, c = t & 7;
    #pragma unroll
    for (int r = 0; r < 2; r++) {
        int row = r * 32 + row0;
        gl_lds16(g + (size_t)row * gstride + ((c ^ (row & 7)) << 3),
                 lds + r * 2048 + ((t >> 6) << 9));   // wave-uniform base; HW adds lane*16B
    }
}

// ---------------- pack x: fp32 -> bf16 ----------------
__global__ void pack_x(const float* __restrict__ src, unsigned short* __restrict__ dst, int n4) {
    int i = blockIdx.x * blockDim.x + threadIdx.x;
    if (i < n4) {
        float4 v = ((const float4*)src)[i];
        ushort4 o;
        o.x = f2bf(v.x); o.y = f2bf(v.y); o.z = f2bf(v.z); o.w = f2bf(v.w);
        ((ushort4*)dst)[i] = o;
    }
}

// ---------------- transpose+pack weights: src (R x C) fp32 -> dst (C x R) bf16 ----------------
__global__ void transpose_pack(const float* __restrict__ src, unsigned short* __restrict__ dst,
                               int R, int C) {
    __shared__ float tile[64][65];
    int t = threadIdx.x;
    int c0 = blockIdx.x * 64, r0 = blockIdx.y * 64;
    int tr = t >> 4, tc4 = (t & 15) * 4;
    #pragma unroll
    for (int p = 0; p < 4; p++) {
        int r = tr + p * 16;
        float4 v = *(const float4*)&src[(size_t)(r0 + r) * C + c0 + tc4];
        tile[r][tc4 + 0] = v.x; tile[r][tc4 + 1] = v.y;
        tile[r][tc4 + 2] = v.z; tile[r][tc4 + 3] = v.w;
    }
    __syncthreads();
    #pragma unroll
    for (int p = 0; p < 4; p++) {
        int rr = tr + p * 16;
        ushort4 o;
        o.x = f2bf(tile[tc4 + 0][rr]);
        o.y = f2bf(tile[tc4 + 1][rr]);
        o.z = f2bf(tile[tc4 + 2][rr]);
        o.w = f2bf(tile[tc4 + 3][rr]);
        *(ushort4*)&dst[(size_t)(c0 + rr) * R + r0 + tc4] = o;
    }
}

// ---------------- QKV GEMM: (8192x768)@(768x2304) -> scatter q,k,vT bf16 ----------------
__global__ __launch_bounds__(256, 2)
void gemm_qkv(const unsigned short* __restrict__ xb, const unsigned short* __restrict__ wT,
              const float* __restrict__ bias,
              unsigned short* __restrict__ qb, unsigned short* __restrict__ kb,
              unsigned short* __restrict__ vb) {
    const int K = 768;
    __shared__ unsigned short As[8192];   // 128 x 64 swizzled
    __shared__ unsigned short Bs[8192];
    int t = threadIdx.x;
    int m0 = blockIdx.x * 128;
    int n0 = blockIdx.y * 128;
    int w = t >> 6, lane = t & 63, l16 = lane & 15, quad = lane >> 4;
    int wm = w >> 1, wn = w & 1;
    const f32x4 zero4 = {0.f, 0.f, 0.f, 0.f};
    f32x4 acc[4][4];
    #pragma unroll
    for (int a = 0; a < 4; a++)
        #pragma unroll
        for (int b = 0; b < 4; b++) acc[a][b] = zero4;

    int row0 = t >> 3, ch = t & 7;
    const unsigned short* gA = xb + (size_t)m0 * K;
    const unsigned short* gB = wT + (size_t)n0 * K;

    for (int k0 = 0; k0 < K; k0 += 64) {
        __syncthreads();
        #pragma unroll
        for (int r = 0; r < 4; r++) {
            int row = r * 32 + row0;
            int gc = k0 + ((ch ^ (row & 7)) << 3);
            gl_lds16(gA + (size_t)row * K + gc, As + r * 2048 + ((t >> 6) << 9));
            gl_lds16(gB + (size_t)row * K + gc, Bs + r * 2048 + ((t >> 6) << 9));
        }
        __syncthreads();
        #pragma unroll
        for (int ks = 0; ks < 2; ks++) {
            bf16x8 af[4], bf[4];
            #pragma unroll
            for (int mi = 0; mi < 4; mi++)
                af[mi] = rd_sw(As, wm * 64 + mi * 16 + l16, ks * 4 + quad);
            #pragma unroll
            for (int ni = 0; ni < 4; ni++)
                bf[ni] = rd_sw(Bs, wn * 64 + ni * 16 + l16, ks * 4 + quad);
            #pragma unroll
            for (int mi = 0; mi < 4; mi++)
                #pragma unroll
                for (int ni = 0; ni < 4; ni++)
                    acc[mi][ni] = __builtin_amdgcn_mfma_f32_16x16x32_bf16(af[mi], bf[ni], acc[mi][ni], 0, 0, 0);
        }
    }

    // epilogue: col n = seg*768 + h*64 + d
    int nb = n0 + wn * 64;
    int seg = nb / 768;
    int nc = nb % 768;
    int h = nc >> 6;
    int bb = m0 >> 10;
    int bh = bb * 12 + h;
    float bv[4];
    #pragma unroll
    for (int ni = 0; ni < 4; ni++) bv[ni] = bias[nb + ni * 16 + l16];

    if (seg < 2) {
        unsigned short* dst = (seg == 0) ? qb : kb;
        #pragma unroll
        for (int mi = 0; mi < 4; mi++) {
            int nrow_base = (m0 & 1023) + wm * 64 + mi * 16 + quad * 4;
            #pragma unroll
            for (int i = 0; i < 4; i++) {
                unsigned short* drow = dst + ((size_t)bh * 1024 + nrow_base + i) * 64;
                #pragma unroll
                for (int ni = 0; ni < 4; ni++)
                    drow[ni * 16 + l16] = f2bf(acc[mi][ni][i] + bv[ni]);
            }
        }
    } else {
        #pragma unroll
        for (int mi = 0; mi < 4; mi++) {
            int nrow0 = (m0 & 1023) + wm * 64 + mi * 16 + quad * 4;
            #pragma unroll
            for (int ni = 0; ni < 4; ni++) {
                int d = ni * 16 + l16;
                ushort4 pk;
                pk.x = f2bf(acc[mi][ni][0] + bv[ni]);
                pk.y = f2bf(acc[mi][ni][1] + bv[ni]);
                pk.z = f2bf(acc[mi][ni][2] + bv[ni]);
                pk.w = f2bf(acc[mi][ni][3] + bv[ni]);
                *(ushort4*)&vb[((size_t)bh * 64 + d) * 1024 + nrow0] = pk;
            }
        }
    }
}

// ---------------- flash attention (S^T form, fixed-max softmax) ----------------
// grid (96, 16): blockIdx.x = b*12+h fast dim -> one (b,h)'s 16 q-blocks share an XCD L2.
__global__ __launch_bounds__(256, 4)
void attn_kernel(const unsigned short* __restrict__ qb, const unsigned short* __restrict__ kb,
                 const unsigned short* __restrict__ vb, const float* __restrict__ temp,
                 unsigned short* __restrict__ attn) {
    __shared__ unsigned short Kt[2][4096];   // 64 keys x 64 d, swizzled
    __shared__ unsigned short Vt[2][4096];   // 64 d x 64 keys, swizzled
    __shared__ unsigned short Ps[4][1024];   // per-wave P^T: 64 keys x 16 q, blocked+swizzled
    int t = threadIdx.x, w = t >> 6, lane = t & 63, l16 = lane & 15, quad = lane >> 4;
    int bh = blockIdx.x, qblk = blockIdx.y;
    int bb = bh / 12, h = bh % 12;
    float tscale = temp[h] * 1.44269504088896f;   // temp * log2(e); softmax in base-2
    int qbase = qblk * 64 + w * 16;

    const unsigned short* kbase = kb + (size_t)bh * 65536;
    const unsigned short* vbase = vb + (size_t)bh * 65536;

    stage64(kbase, 64, Kt[0], t);
    stage64(vbase, 1024, Vt[0], t);

    // Q as B-operand: b[j] = Q[q=l16][d=quad*8+j (+32)]
    const unsigned short* qrow = qb + ((size_t)bh * 1024 + qbase + l16) * 64;
    bf16x8 bq0 = *(const bf16x8*)&qrow[quad * 8];
    bf16x8 bq1 = *(const bf16x8*)&qrow[32 + quad * 8];

    bf16x8 aone;
    #pragma unroll
    for (int j = 0; j < 8; j++) aone[j] = (short)0x3F80;   // bf16 1.0

    const f32x4 zero4 = {0.f, 0.f, 0.f, 0.f};
    f32x4 Oacc[4];      // O^T: rows = d (per 16-d tile), cols = q
    f32x4 Osum = zero4; // denominator via ones-MFMA (all regs identical per lane)
    #pragma unroll
    for (int ti = 0; ti < 4; ti++) Oacc[ti] = zero4;

    unsigned short* pw = Ps[w];

    // P^T LDS layout: addr(key,q) = qp*128 + ((q + 2*qp)&15)*8 + (key&7), qp = key>>3.
    // Loop-invariant addresses:
    int bw_[4];
    #pragma unroll
    for (int ni = 0; ni < 4; ni++) {
        int qp = ni * 2 + (quad >> 1);
        bw_[ni] = qp * 128 + ((l16 + 2 * qp) & 15) * 8 + (quad & 1) * 4;
    }
    int qp0 = quad, qp1 = 4 + quad;
    int br0 = qp0 * 128 + ((l16 + 2 * qp0) & 15) * 8;
    int br1 = qp1 * 128 + ((l16 + 2 * qp1) & 15) * 8;

    bool eq[4];
    #pragma unroll
    for (int i = 0; i < 4; i++) eq[i] = (l16 == quad * 4 + i);

    for (int kt = 0; kt < 16; kt++) {
        int cur = kt & 1;
        __syncthreads();                       // prefetch (kt) drained; prev reads done
        if (kt < 15) {                         // distance-1 prefetch into other buffer
            stage64(kbase + (size_t)(kt + 1) * 4096, 64, Kt[cur ^ 1], t);
            stage64(vbase + (size_t)(kt + 1) * 64, 1024, Vt[cur ^ 1], t);
        }
        const unsigned short* Kc = Kt[cur];
        const unsigned short* Vc = Vt[cur];

        // S^T = K Q^T : per ni, 16 keys x 16 q. C-layout: col=q(l16), row=key(quad*4+i).
        #pragma unroll
        for (int ni = 0; ni < 4; ni++) {
            bf16x8 ak0 = rd_sw(Kc, ni * 16 + l16, quad);
            bf16x8 ak1 = rd_sw(Kc, ni * 16 + l16, 4 + quad);
            f32x4 z = zero4;
            z = __builtin_amdgcn_mfma_f32_16x16x32_bf16(ak0, bq0, z, 0, 0, 0);
            z = __builtin_amdgcn_mfma_f32_16x16x32_bf16(ak1, bq1, z, 0, 0, 0);
            bool dw = (kt == qblk) && (ni == w);
            float p0 = exp2f(z[0] * tscale);
            float p1 = exp2f(z[1] * tscale);
            float p2 = exp2f(z[2] * tscale);
            float p3 = exp2f(z[3] * tscale);
            if (dw) {   // diagonal: key==q only possible in this (ni==w) slice
                if (eq[0]) p0 = 0.f;
                if (eq[1]) p1 = 0.f;
                if (eq[2]) p2 = 0.f;
                if (eq[3]) p3 = 0.f;
            }
            union { ushort4 u; __hip_bfloat162 h[2]; } pk;
            pk.h[0] = __float22bfloat162_rn(make_float2(p0, p1));
            pk.h[1] = __float22bfloat162_rn(make_float2(p2, p3));
            *(ushort4*)&pw[bw_[ni]] = pk.u;
        }

        // P^T B-frags (shared across d-tiles): keys quad*8+j (+32)
        bf16x8 pt0 = *(const bf16x8*)&pw[br0];
        bf16x8 pt1 = *(const bf16x8*)&pw[br1];

        // denominator: ones * P^T
        Osum = __builtin_amdgcn_mfma_f32_16x16x32_bf16(aone, pt0, Osum, 0, 0, 0);
        Osum = __builtin_amdgcn_mfma_f32_16x16x32_bf16(aone, pt1, Osum, 0, 0, 0);

        // O^T += V^T P^T
        #pragma unroll
        for (int ti = 0; ti < 4; ti++) {
            bf16x8 av0 = rd_sw(Vc, ti * 16 + l16, quad);
            bf16x8 av1 = rd_sw(Vc, ti * 16 + l16, 4 + quad);
            Oacc[ti] = __builtin_amdgcn_mfma_f32_16x16x32_bf16(av0, pt0, Oacc[ti], 0, 0, 0);
            Oacc[ti] = __builtin_amdgcn_mfma_f32_16x16x32_bf16(av1, pt1, Oacc[ti], 0, 0, 0);
        }
    }

    // epilogue: O^T lane holds q=l16, d=ti*16+quad*4+i  -> 4 contiguous d per reg group
    float inv = 1.0f / Osum[0];
    int orow = bb * 1024 + qbase + l16;
    #pragma unroll
    for (int ti = 0; ti < 4; ti++) {
        union { ushort4 u; __hip_bfloat162 h[2]; } pk;
        pk.h[0] = __float22bfloat162_rn(make_float2(Oacc[ti][0] * inv, Oacc[ti][1] * inv));
        pk.h[1] = __float22bfloat162_rn(make_float2(Oacc[ti][2] * inv, Oacc[ti][3] * inv));
        int col = h * 64 + ti * 16 + quad * 4;
        *(ushort4*)&attn[(size_t)orow * 768 + col] = pk.u;
    }
}

// ---------------- proj GEMM: (8192x768)@(768x768) + bias -> fp32 out ----------------
__global__ __launch_bounds__(256, 2)
void gemm_proj(const unsigned short* __restrict__ ab, const unsigned short* __restrict__ wT,
               const float* __restrict__ bias, float* __restrict__ out) {
    const int K = 768;
    __shared__ unsigned short As[8192];
    __shared__ unsigned short Bs[8192];
    int t = threadIdx.x;
    int m0 = blockIdx.x * 128;
    int n0 = blockIdx.y * 128;
    int w = t >> 6, lane = t & 63, l16 = lane & 15, quad = lane >> 4;
    int wm = w >> 1, wn = w & 1;
    const f32x4 zero4 = {0.f, 0.f, 0.f, 0.f};
    f32x4 acc[4][4];
    #pragma unroll
    for (int a = 0; a < 4; a++)
        #pragma unroll
        for (int b = 0; b < 4; b++) acc[a][b] = zero4;

    int row0 = t >> 3, ch = t & 7;
    const unsigned short* gA = ab + (size_t)m0 * K;
    const unsigned short* gB = wT + (size_t)n0 * K;

    for (int k0 = 0; k0 < K; k0 += 64) {
        __syncthreads();
        #pragma unroll
        for (int r = 0; r < 4; r++) {
            int row = r * 32 + row0;
            int gc = k0 + ((ch ^ (row & 7)) << 3);
            gl_lds16(gA + (size_t)row * K + gc, As + r * 2048 + ((t >> 6) << 9));
            gl_lds16(gB + (size_t)row * K + gc, Bs + r * 2048 + ((t >> 6) << 9));
        }
        __syncthreads();
        #pragma unroll
        for (int ks = 0; ks < 2; ks++) {
            bf16x8 af[4], bf[4];
            #pragma unroll
            for (int mi = 0; mi < 4; mi++)
                af[mi] = rd_sw(As, wm * 64 + mi * 16 + l16, ks * 4 + quad);
            #pragma unroll
            for (int ni = 0; ni < 4; ni++)
                bf[ni] = rd_sw(Bs, wn * 64 + ni * 16 + l16, ks * 4 + quad);
            #pragma unroll
            for (int mi = 0; mi < 4; mi++)
                #pragma unroll
                for (int ni = 0; ni < 4; ni++)
                    acc[mi][ni] = __builtin_amdgcn_mfma_f32_16x16x32_bf16(af[mi], bf[ni], acc[mi][ni], 0, 0, 0);
        }
    }

    #pragma unroll
    for (int mi = 0; mi < 4; mi++)
        #pragma unroll
        for (int i = 0; i < 4; i++) {
            int row = m0 + wm * 64 + mi * 16 + quad * 4 + i;
            float* orow = out + (size_t)row * 768;
            #pragma unroll
            for (int ni = 0; ni < 4; ni++) {
                int col = n0 + wn * 64 + ni * 16 + l16;
                orow[col] = acc[mi][ni][i] + bias[col];
            }
        }
}

extern "C" void kernel_launch(void* const* d_in, const int* in_sizes, int n_in,
                              void* d_out, int out_size, void* d_ws, size_t ws_size,
                              hipStream_t stream) {
    const float* x      = (const float*)d_in[0];
    const float* w_qkv  = (const float*)d_in[1];
    const float* b_qkv  = (const float*)d_in[2];
    const float* w_proj = (const float*)d_in[3];
    const float* b_proj = (const float*)d_in[4];
    const float* temp   = (const float*)d_in[5];
    float* out = (float*)d_out;

    char* ws = (char*)d_ws;
    unsigned short* xb     = (unsigned short*)(ws);                 // 8192x768 bf16
    unsigned short* wqkvT  = (unsigned short*)(ws + 12582912);      // 2304x768 bf16
    unsigned short* wprojT = (unsigned short*)(ws + 16121856);      // 768x768 bf16
    unsigned short* qb     = (unsigned short*)(ws + 17301504);      // (B H N D) bf16
    unsigned short* kb     = (unsigned short*)(ws + 29884416);      // (B H N D) bf16
    unsigned short* vb     = (unsigned short*)(ws + 42467328);      // (B H D N) bf16
    unsigned short* attn   = (unsigned short*)(ws + 55050240);      // 8192x768 bf16

    pack_x<<<6144, 256, 0, stream>>>(x, xb, 1572864);
    transpose_pack<<<dim3(36, 12), 256, 0, stream>>>(w_qkv, wqkvT, 768, 2304);
    transpose_pack<<<dim3(12, 12), 256, 0, stream>>>(w_proj, wprojT, 768, 768);
    gemm_qkv<<<dim3(64, 18), 256, 0, stream>>>(xb, wqkvT, b_qkv, qb, kb, vb);
    attn_kernel<<<dim3(96, 16), 256, 0, stream>>>(qb, kb, vb, temp, attn);
    gemm_proj<<<dim3(64, 6), 256, 0, stream>>>(attn, wprojT, b_proj, out);
}

// Round 4
// 188.183 us; speedup vs baseline: 2.0151x; 1.1062x over previous
//
#include <hip/hip_runtime.h>
#include <hip/hip_bf16.h>

// B=8 N=1024 C=768 H=12 D=64.  All MFMA: v_mfma_f32_16x16x32_bf16.
// Frag layouts (verified): A: m=lane&15, k=quad*8+j ; B: n=lane&15, k=quad*8+j ;
// C/D: col=lane&15, row=quad*4+reg.
//
// Attention: S^T = K·Q^T (A=K, B=Q) -> C-layout has q on lanes, keys on regs.
// PV uses a PERMUTED contraction index k = bits[n1 q1 q0 n0 c e] of key
// (key bits [n1 n0 q1 q0 c e], ni=n1n0, quad=q1q0, reg-pair=c, e=low bit).
// Under this permutation the packed exp(S^T) registers ARE the PV B-fragments
// (no LDS round-trip, no shuffles). V's columns are stored pre-permuted by
// gemm_qkv's epilogue so A-frags of V^T line up with the same k.
// Softmax uses fixed max 0 (scores bounded ~2^36 in exp2 domain; num/denom
// share bf16 P so scaling cancels). temp*log2e is pre-folded into q.
//
// K/V LDS tiles: stride-64 shorts, XOR swizzle (row,chunk)->row*64+((chunk^(row&7))<<3);
// keeps global_load_lds legal (wave-uniform dst), caps ds conflicts at 2-way (free).

typedef __attribute__((ext_vector_type(8))) short bf16x8;
typedef __attribute__((ext_vector_type(4))) float f32x4;

__device__ __forceinline__ unsigned short f2bf(float f) {
    union { float f; unsigned u; } v; v.f = f;
    unsigned r = v.u + 0x7fff + ((v.u >> 16) & 1);   // RNE
    return (unsigned short)(r >> 16);
}

__device__ __forceinline__ unsigned pack2(float a, float b) {
    union { __hip_bfloat162 h; unsigned u; } c;
    c.h = __float22bfloat162_rn(make_float2(a, b));   // .x -> low short
    return c.u;
}

__device__ __forceinline__ void gl_lds16(const unsigned short* g, unsigned short* l) {
    __builtin_amdgcn_global_load_lds(
        (const __attribute__((address_space(1))) void*)g,
        (__attribute__((address_space(3))) void*)l, 16, 0, 0);
}

__device__ __forceinline__ bf16x8 rd_sw(const unsigned short* lds, int row, int chunk) {
    return *(const bf16x8*)&lds[row * 64 + (((chunk ^ (row & 7))) << 3)];
}

// stage a 64-row x 64-short tile (row stride gstride shorts) into swizzled LDS (8KB)
__device__ __forceinline__ void stage64(const unsigned short* g, int gstride,
                                        unsigned short* lds, int t) {
    int row0 = t >> 3, c = t & 7;
    #pragma unroll
    for (int r = 0; r < 2; r++) {
        int row = r * 32 + row0;
        gl_lds16(g + (size_t)row * gstride + ((c ^ (row & 7)) << 3),
                 lds + r * 2048 + ((t >> 6) << 9));   // wave-uniform base; HW adds lane*16B
    }
}

// ---------------- fused prep: pack x + transpose both weights ----------------
__global__ void prep(const float* __restrict__ x, const float* __restrict__ w_qkv,
                     const float* __restrict__ w_proj,
                     unsigned short* __restrict__ xb, unsigned short* __restrict__ wqkvT,
                     unsigned short* __restrict__ wprojT) {
    int b = blockIdx.x, t = threadIdx.x;
    if (b < 6144) {                       // pack x: 6144*256 float4s
        int i = b * 256 + t;
        float4 v = ((const float4*)x)[i];
        ushort4 o;
        o.x = f2bf(v.x); o.y = f2bf(v.y); o.z = f2bf(v.z); o.w = f2bf(v.w);
        ((ushort4*)xb)[i] = o;
        return;
    }
    const float* src; unsigned short* dst; int R, C, bx, by;
    if (b < 6576) { int b2 = b - 6144; src = w_qkv; dst = wqkvT; R = 768; C = 2304; bx = b2 % 36; by = b2 / 36; }
    else          { int b3 = b - 6576; src = w_proj; dst = wprojT; R = 768; C = 768;  bx = b3 % 12; by = b3 / 12; }
    __shared__ float tile[64][65];
    int c0 = bx * 64, r0 = by * 64;
    int tr = t >> 4, tc4 = (t & 15) * 4;
    #pragma unroll
    for (int p = 0; p < 4; p++) {
        int r = tr + p * 16;
        float4 v = *(const float4*)&src[(size_t)(r0 + r) * C + c0 + tc4];
        tile[r][tc4 + 0] = v.x; tile[r][tc4 + 1] = v.y;
        tile[r][tc4 + 2] = v.z; tile[r][tc4 + 3] = v.w;
    }
    __syncthreads();
    #pragma unroll
    for (int p = 0; p < 4; p++) {
        int rr = tr + p * 16;
        ushort4 o;
        o.x = f2bf(tile[tc4 + 0][rr]);
        o.y = f2bf(tile[tc4 + 1][rr]);
        o.z = f2bf(tile[tc4 + 2][rr]);
        o.w = f2bf(tile[tc4 + 3][rr]);
        *(ushort4*)&dst[(size_t)(c0 + rr) * R + r0 + tc4] = o;
    }
}

// ---------------- QKV GEMM: (8192x768)@(768x2304) -> scatter q,k,vT bf16 ----------------
// q is pre-scaled by temp[h]*log2(e); vT columns are stored k-permuted (see header).
__global__ __launch_bounds__(256, 2)
void gemm_qkv(const unsigned short* __restrict__ xb, const unsigned short* __restrict__ wT,
              const float* __restrict__ bias, const float* __restrict__ temp,
              unsigned short* __restrict__ qb, unsigned short* __restrict__ kb,
              unsigned short* __restrict__ vb) {
    const int K = 768;
    __shared__ unsigned short As[8192];   // 128 x 64 swizzled
    __shared__ unsigned short Bs[8192];
    int t = threadIdx.x;
    int m0 = blockIdx.x * 128;
    int n0 = blockIdx.y * 128;
    int w = t >> 6, lane = t & 63, l16 = lane & 15, quad = lane >> 4;
    int wm = w >> 1, wn = w & 1;
    const f32x4 zero4 = {0.f, 0.f, 0.f, 0.f};
    f32x4 acc[4][4];
    #pragma unroll
    for (int a = 0; a < 4; a++)
        #pragma unroll
        for (int b = 0; b < 4; b++) acc[a][b] = zero4;

    int row0 = t >> 3, ch = t & 7;
    const unsigned short* gA = xb + (size_t)m0 * K;
    const unsigned short* gB = wT + (size_t)n0 * K;

    for (int k0 = 0; k0 < K; k0 += 64) {
        __syncthreads();
        #pragma unroll
        for (int r = 0; r < 4; r++) {
            int row = r * 32 + row0;
            int gc = k0 + ((ch ^ (row & 7)) << 3);
            gl_lds16(gA + (size_t)row * K + gc, As + r * 2048 + ((t >> 6) << 9));
            gl_lds16(gB + (size_t)row * K + gc, Bs + r * 2048 + ((t >> 6) << 9));
        }
        __syncthreads();
        #pragma unroll
        for (int ks = 0; ks < 2; ks++) {
            bf16x8 af[4], bf[4];
            #pragma unroll
            for (int mi = 0; mi < 4; mi++)
                af[mi] = rd_sw(As, wm * 64 + mi * 16 + l16, ks * 4 + quad);
            #pragma unroll
            for (int ni = 0; ni < 4; ni++)
                bf[ni] = rd_sw(Bs, wn * 64 + ni * 16 + l16, ks * 4 + quad);
            #pragma unroll
            for (int mi = 0; mi < 4; mi++)
                #pragma unroll
                for (int ni = 0; ni < 4; ni++)
                    acc[mi][ni] = __builtin_amdgcn_mfma_f32_16x16x32_bf16(af[mi], bf[ni], acc[mi][ni], 0, 0, 0);
        }
    }

    // epilogue: col n = seg*768 + h*64 + d
    int nb = n0 + wn * 64;
    int seg = nb / 768;
    int nc = nb % 768;
    int h = nc >> 6;
    int bb = m0 >> 10;
    int bh = bb * 12 + h;
    float bv[4];
    #pragma unroll
    for (int ni = 0; ni < 4; ni++) bv[ni] = bias[nb + ni * 16 + l16];

    if (seg < 2) {
        unsigned short* dst = (seg == 0) ? qb : kb;
        float scale = (seg == 0) ? temp[h] * 1.44269504088896f : 1.0f;
        #pragma unroll
        for (int mi = 0; mi < 4; mi++) {
            int nrow_base = (m0 & 1023) + wm * 64 + mi * 16 + quad * 4;
            #pragma unroll
            for (int i = 0; i < 4; i++) {
                unsigned short* drow = dst + ((size_t)bh * 1024 + nrow_base + i) * 64;
                #pragma unroll
                for (int ni = 0; ni < 4; ni++)
                    drow[ni * 16 + l16] = f2bf((acc[mi][ni][i] + bv[ni]) * scale);
            }
        }
    } else {
        #pragma unroll
        for (int mi = 0; mi < 4; mi++) {
            int nrow0 = (m0 & 1023) + wm * 64 + mi * 16 + quad * 4;
            // k-permuted column: key bits [n1 n0 q1 q0 c e] -> col bits [n1 q1 q0 n0 c e]
            int nl = nrow0 & 63;
            int ncol = (nrow0 & 960) + (nl & 32) + ((nl & 12) << 1) + ((nl & 16) >> 2);
            #pragma unroll
            for (int ni = 0; ni < 4; ni++) {
                int d = ni * 16 + l16;
                ushort4 pk;
                pk.x = f2bf(acc[mi][ni][0] + bv[ni]);
                pk.y = f2bf(acc[mi][ni][1] + bv[ni]);
                pk.z = f2bf(acc[mi][ni][2] + bv[ni]);
                pk.w = f2bf(acc[mi][ni][3] + bv[ni]);
                *(ushort4*)&vb[((size_t)bh * 64 + d) * 1024 + ncol] = pk;
            }
        }
    }
}

// ---------------- flash attention: 128 q/block, 32 q/wave, register-only P ----------------
// grid (96, 8): blockIdx.x = b*12+h fast dim -> one (b,h)'s q-blocks share an XCD L2.
__global__ __launch_bounds__(256, 4)
void attn_kernel(const unsigned short* __restrict__ qb, const unsigned short* __restrict__ kb,
                 const unsigned short* __restrict__ vb,
                 unsigned short* __restrict__ attn) {
    __shared__ unsigned short Kt[2][4096];   // 64 keys x 64 d, swizzled
    __shared__ unsigned short Vt[2][4096];   // 64 d x 64 k(perm), swizzled
    int t = threadIdx.x, w = t >> 6, lane = t & 63, l16 = lane & 15, quad = lane >> 4;
    int bh = blockIdx.x, qblk = blockIdx.y;
    int bb = bh / 12, h = bh % 12;
    int qbase = qblk * 128 + w * 32;         // wave's 32-q base within (b,h)

    const unsigned short* kbase = kb + (size_t)bh * 65536;
    const unsigned short* vbase = vb + (size_t)bh * 65536;

    stage64(kbase, 64, Kt[0], t);
    stage64(vbase, 1024, Vt[0], t);

    // Q B-frags (pre-scaled by temp*log2e): qh in {0,1}, d-halves kh in {0,1}
    bf16x8 bq[2][2];
    #pragma unroll
    for (int qh = 0; qh < 2; qh++) {
        const unsigned short* qrow = qb + ((size_t)bh * 1024 + qbase + qh * 16 + l16) * 64;
        bq[qh][0] = *(const bf16x8*)&qrow[quad * 8];
        bq[qh][1] = *(const bf16x8*)&qrow[32 + quad * 8];
    }

    bf16x8 aone;
    #pragma unroll
    for (int j = 0; j < 8; j++) aone[j] = (short)0x3F80;   // bf16 1.0

    const f32x4 zero4 = {0.f, 0.f, 0.f, 0.f};
    f32x4 Oacc[2][4];     // [qh][ti] O^T: rows=d, cols=q
    f32x4 Osum[2];
    #pragma unroll
    for (int qh = 0; qh < 2; qh++) {
        Osum[qh] = zero4;
        #pragma unroll
        for (int ti = 0; ti < 4; ti++) Oacc[qh][ti] = zero4;
    }

    int ktd = qbase >> 6;                    // the kt tile containing this wave's diagonal
    bool eq[4];
    #pragma unroll
    for (int i = 0; i < 4; i++) eq[i] = (l16 == quad * 4 + i);

    for (int kt = 0; kt < 16; kt++) {
        int cur = kt & 1;
        __syncthreads();                     // prefetch(kt) drained; prev reads done
        if (kt < 15) {
            stage64(kbase + (size_t)(kt + 1) * 4096, 64, Kt[cur ^ 1], t);
            stage64(vbase + (size_t)(kt + 1) * 64, 1024, Vt[cur ^ 1], t);
        }
        const unsigned short* Kc = Kt[cur];
        const unsigned short* Vc = Vt[cur];

        // S^T per ni (16 keys) x both q-halves; exp2 inline; pack to PV B-frag dwords.
        unsigned pk[2][4][2];                // [qh][ni][c]: keys {ni*16+quad*4+2c, +1}, q=l16
        #pragma unroll
        for (int ni = 0; ni < 4; ni++) {
            bf16x8 ak0 = rd_sw(Kc, ni * 16 + l16, quad);
            bf16x8 ak1 = rd_sw(Kc, ni * 16 + l16, 4 + quad);
            #pragma unroll
            for (int qh = 0; qh < 2; qh++) {
                f32x4 z = zero4;
                z = __builtin_amdgcn_mfma_f32_16x16x32_bf16(ak0, bq[qh][0], z, 0, 0, 0);
                z = __builtin_amdgcn_mfma_f32_16x16x32_bf16(ak1, bq[qh][1], z, 0, 0, 0);
                float p0 = exp2f(z[0]);
                float p1 = exp2f(z[1]);
                float p2 = exp2f(z[2]);
                float p3 = exp2f(z[3]);
                if (kt == ktd && ni == ((w * 2 + qh) & 3)) {   // diagonal slice
                    if (eq[0]) p0 = 0.f;
                    if (eq[1]) p1 = 0.f;
                    if (eq[2]) p2 = 0.f;
                    if (eq[3]) p3 = 0.f;
                }
                pk[qh][ni][0] = pack2(p0, p1);
                pk[qh][ni][1] = pack2(p2, p3);
            }
        }

        // PV B-frags are the pk registers directly under the k-permutation.
        union { unsigned u[4]; bf16x8 b; } pt[2][2];
        #pragma unroll
        for (int qh = 0; qh < 2; qh++) {
            pt[qh][0].u[0] = pk[qh][0][0]; pt[qh][0].u[1] = pk[qh][0][1];
            pt[qh][0].u[2] = pk[qh][1][0]; pt[qh][0].u[3] = pk[qh][1][1];
            pt[qh][1].u[0] = pk[qh][2][0]; pt[qh][1].u[1] = pk[qh][2][1];
            pt[qh][1].u[2] = pk[qh][3][0]; pt[qh][1].u[3] = pk[qh][3][1];
            // denominator: ones x P^T (permutation-invariant)
            Osum[qh] = __builtin_amdgcn_mfma_f32_16x16x32_bf16(aone, pt[qh][0].b, Osum[qh], 0, 0, 0);
            Osum[qh] = __builtin_amdgcn_mfma_f32_16x16x32_bf16(aone, pt[qh][1].b, Osum[qh], 0, 0, 0);
        }

        // O^T += V^T P^T  (V columns pre-permuted to k-order)
        #pragma unroll
        for (int ti = 0; ti < 4; ti++) {
            bf16x8 av0 = rd_sw(Vc, ti * 16 + l16, quad);
            bf16x8 av1 = rd_sw(Vc, ti * 16 + l16, 4 + quad);
            #pragma unroll
            for (int qh = 0; qh < 2; qh++) {
                Oacc[qh][ti] = __builtin_amdgcn_mfma_f32_16x16x32_bf16(av0, pt[qh][0].b, Oacc[qh][ti], 0, 0, 0);
                Oacc[qh][ti] = __builtin_amdgcn_mfma_f32_16x16x32_bf16(av1, pt[qh][1].b, Oacc[qh][ti], 0, 0, 0);
            }
        }
    }

    // epilogue: lane holds q=l16 (per qh), d = ti*16 + quad*4 + i -> ushort4 stores
    #pragma unroll
    for (int qh = 0; qh < 2; qh++) {
        float inv = 1.0f / Osum[qh][0];
        int orow = bb * 1024 + qbase + qh * 16 + l16;
        #pragma unroll
        for (int ti = 0; ti < 4; ti++) {
            ushort4 pk4;
            pk4.x = (unsigned short)(pack2(Oacc[qh][ti][0] * inv, Oacc[qh][ti][1] * inv) & 0xffff);
            pk4.y = (unsigned short)(pack2(Oacc[qh][ti][0] * inv, Oacc[qh][ti][1] * inv) >> 16);
            pk4.z = (unsigned short)(pack2(Oacc[qh][ti][2] * inv, Oacc[qh][ti][3] * inv) & 0xffff);
            pk4.w = (unsigned short)(pack2(Oacc[qh][ti][2] * inv, Oacc[qh][ti][3] * inv) >> 16);
            int col = h * 64 + ti * 16 + quad * 4;
            *(ushort4*)&attn[(size_t)orow * 768 + col] = pk4;
        }
    }
}

// ---------------- proj GEMM: (8192x768)@(768x768) + bias -> fp32 out ----------------
__global__ __launch_bounds__(256, 2)
void gemm_proj(const unsigned short* __restrict__ ab, const unsigned short* __restrict__ wT,
               const float* __restrict__ bias, float* __restrict__ out) {
    const int K = 768;
    __shared__ unsigned short As[8192];
    __shared__ unsigned short Bs[8192];
    int t = threadIdx.x;
    int m0 = blockIdx.x * 128;
    int n0 = blockIdx.y * 128;
    int w = t >> 6, lane = t & 63, l16 = lane & 15, quad = lane >> 4;
    int wm = w >> 1, wn = w & 1;
    const f32x4 zero4 = {0.f, 0.f, 0.f, 0.f};
    f32x4 acc[4][4];
    #pragma unroll
    for (int a = 0; a < 4; a++)
        #pragma unroll
        for (int b = 0; b < 4; b++) acc[a][b] = zero4;

    int row0 = t >> 3, ch = t & 7;
    const unsigned short* gA = ab + (size_t)m0 * K;
    const unsigned short* gB = wT + (size_t)n0 * K;

    for (int k0 = 0; k0 < K; k0 += 64) {
        __syncthreads();
        #pragma unroll
        for (int r = 0; r < 4; r++) {
            int row = r * 32 + row0;
            int gc = k0 + ((ch ^ (row & 7)) << 3);
            gl_lds16(gA + (size_t)row * K + gc, As + r * 2048 + ((t >> 6) << 9));
            gl_lds16(gB + (size_t)row * K + gc, Bs + r * 2048 + ((t >> 6) << 9));
        }
        __syncthreads();
        #pragma unroll
        for (int ks = 0; ks < 2; ks++) {
            bf16x8 af[4], bf[4];
            #pragma unroll
            for (int mi = 0; mi < 4; mi++)
                af[mi] = rd_sw(As, wm * 64 + mi * 16 + l16, ks * 4 + quad);
            #pragma unroll
            for (int ni = 0; ni < 4; ni++)
                bf[ni] = rd_sw(Bs, wn * 64 + ni * 16 + l16, ks * 4 + quad);
            #pragma unroll
            for (int mi = 0; mi < 4; mi++)
                #pragma unroll
                for (int ni = 0; ni < 4; ni++)
                    acc[mi][ni] = __builtin_amdgcn_mfma_f32_16x16x32_bf16(af[mi], bf[ni], acc[mi][ni], 0, 0, 0);
        }
    }

    #pragma unroll
    for (int mi = 0; mi < 4; mi++)
        #pragma unroll
        for (int i = 0; i < 4; i++) {
            int row = m0 + wm * 64 + mi * 16 + quad * 4 + i;
            float* orow = out + (size_t)row * 768;
            #pragma unroll
            for (int ni = 0; ni < 4; ni++) {
                int col = n0 + wn * 64 + ni * 16 + l16;
                orow[col] = acc[mi][ni][i] + bias[col];
            }
        }
}

extern "C" void kernel_launch(void* const* d_in, const int* in_sizes, int n_in,
                              void* d_out, int out_size, void* d_ws, size_t ws_size,
                              hipStream_t stream) {
    const float* x      = (const float*)d_in[0];
    const float* w_qkv  = (const float*)d_in[1];
    const float* b_qkv  = (const float*)d_in[2];
    const float* w_proj = (const float*)d_in[3];
    const float* b_proj = (const float*)d_in[4];
    const float* temp   = (const float*)d_in[5];
    float* out = (float*)d_out;

    char* ws = (char*)d_ws;
    unsigned short* xb     = (unsigned short*)(ws);                 // 8192x768 bf16
    unsigned short* wqkvT  = (unsigned short*)(ws + 12582912);      // 2304x768 bf16
    unsigned short* wprojT = (unsigned short*)(ws + 16121856);      // 768x768 bf16
    unsigned short* qb     = (unsigned short*)(ws + 17301504);      // (B H N D) bf16, pre-scaled
    unsigned short* kb     = (unsigned short*)(ws + 29884416);      // (B H N D) bf16
    unsigned short* vb     = (unsigned short*)(ws + 42467328);      // (B H D N) bf16, k-permuted cols
    unsigned short* attn   = (unsigned short*)(ws + 55050240);      // 8192x768 bf16

    prep<<<6720, 256, 0, stream>>>(x, w_qkv, w_proj, xb, wqkvT, wprojT);
    gemm_qkv<<<dim3(64, 18), 256, 0, stream>>>(xb, wqkvT, b_qkv, temp, qb, kb, vb);
    attn_kernel<<<dim3(96, 8), 256, 0, stream>>>(qb, kb, vb, attn);
    gemm_proj<<<dim3(64, 6), 256, 0, stream>>>(attn, wprojT, b_proj, out);
}